// Round 10
// baseline (144.389 us; speedup 1.0000x reference)
//
#include <hip/hip_runtime.h>

#define CLS 64
#define DIM 128
#define NROWS 262144
#define MARGIN 1.4f
#define EPSF 1e-6f
#define NBLK 256                   // 256 blocks x 512 thr (8 waves)
#define TPAD 132                   // padded tree row / staging slot pitch
#define SPITCH 132                 // staging: [16 slots][132] u32, pitch 132

typedef __attribute__((ext_vector_type(8))) short bf16x8;
typedef __attribute__((ext_vector_type(4))) float f32x4;

union BFrag { unsigned u[4]; bf16x8 v; };

// pack two fp32 into (bf16(hi)<<16)|bf16(lo) by truncation
__device__ __forceinline__ unsigned pack_bf16(float hi, float lo) {
    return (__float_as_uint(hi) & 0xFFFF0000u) | (__float_as_uint(lo) >> 16);
}

// ---------------- Phase A: one-hot MFMA class sums; coalesced loads + slot-major LDS staging ----------------
// Wave w owns rows [(b*8+w)*128, +128), 4 K-steps of 32 rows.
// Staging per wave: [16 slots][SPITCH] u32. Slot s = 2m'+h holds rows (4m'+h, 4m'+h+2) packed (lo,hi).
//   write: lane (h,c) -> one ds_write_b128 at dword 132*s + 4c  (canonical conflict-free pattern)
//   read:  B[dt].u[j] = stage[(4lg+j)*132 + dt*16 + li]          (uniform 2-way = free)
__global__ __launch_bounds__(512, 2) void phaseA(const float* __restrict__ emb,
                                                 const int* __restrict__ tgt,
                                                 float* __restrict__ psum,
                                                 int* __restrict__ pcnt,
                                                 float* __restrict__ psq) {
    __shared__ __align__(16) unsigned sbuf[2 * CLS * TPAD];  // 16896 u32 = 8 waves x 16 x 132
    __shared__ int cnt[CLS];
    __shared__ float lred[8];

    const int tid = threadIdx.x;
    const int w = tid >> 6;          // wave 0..7
    const int l = tid & 63;
    const int h = l >> 5;            // row-parity half
    const int c = l & 31;            // dim-quad 0..31
    const int lg = (l >> 4) & 3;     // lane-group (k-block)
    const int li = l & 15;           // M/N lane index

    if (tid < CLS) cnt[tid] = 0;
    __syncthreads();

    unsigned* __restrict__ stage = &sbuf[w * (16 * SPITCH)];

    f32x4 acc[4][8];
#pragma unroll
    for (int ct = 0; ct < 4; ++ct)
#pragma unroll
        for (int dt = 0; dt < 8; ++dt) {
            f32x4 z = {0.f, 0.f, 0.f, 0.f};
            acc[ct][dt] = z;
        }

    float sq0 = 0.f, sq1 = 0.f;
    const float4* __restrict__ embv = reinterpret_cast<const float4*>(emb);
    const int wrow = blockIdx.x * 1024 + w * 128;

#pragma unroll
    for (int t = 0; t < 4; ++t) {
        const int rb = wrow + t * 32;

        // per-class counts (1 LDS-atomic instr per K-step)
        if (l < 32) atomicAdd(&cnt[tgt[rb + l]], 1);

        // tgt for this lane-group's 8 rows
        const int4* tp = reinterpret_cast<const int4*>(tgt + rb + lg * 8);
        const int4 ta = tp[0], tb = tp[1];
        const int tg[8] = {ta.x, ta.y, ta.z, ta.w, tb.x, tb.y, tb.z, tb.w};

        // ---- stage 32 rows x 128 dims: coalesced float4 loads -> slot-major bf16 LDS ----
        const size_t fb = (size_t)rb * 32;    // float4 index of tile base
#pragma unroll
        for (int half = 0; half < 2; ++half) {
            float4 f[8];
#pragma unroll
            for (int i = 0; i < 8; ++i) f[i] = embv[fb + (size_t)(half * 8 + i) * 64 + l];
#pragma unroll
            for (int i = 0; i < 8; ++i) {
                sq0 += f[i].x * f[i].x + f[i].y * f[i].y;
                sq1 += f[i].z * f[i].z + f[i].w * f[i].w;
            }
            // pair (f[2m], f[2m+1]) = rows (4m'+h, 4m'+h+2), m' = half*4+m; slot s = 2m'+h
#pragma unroll
            for (int m = 0; m < 4; ++m) {
                const int s = (half * 4 + m) * 2 + h;
                const float4 lo = f[2 * m];
                const float4 hi = f[2 * m + 1];
                uint4 pk;
                pk.x = pack_bf16(hi.x, lo.x);
                pk.y = pack_bf16(hi.y, lo.y);
                pk.z = pack_bf16(hi.z, lo.z);
                pk.w = pack_bf16(hi.w, lo.w);
                *reinterpret_cast<uint4*>(&stage[s * SPITCH + 4 * c]) = pk;   // ds_write_b128
            }
        }

        // ---- B fragments: slots 4lg..4lg+3 at d = dt*16+li (2-way banks = free) ----
        BFrag B[8];
#pragma unroll
        for (int dt = 0; dt < 8; ++dt) {
            const int d = dt * 16 + li;
#pragma unroll
            for (int j = 0; j < 4; ++j) B[dt].u[j] = stage[(4 * lg + j) * SPITCH + d];
        }

        // ---- A (one-hot, k-slot j -> rows {(0,2),(1,3),(4,6),(5,7)}+8lg) + MFMA ----
#pragma unroll
        for (int ct = 0; ct < 4; ++ct) {
            const int cls = ct * 16 + li;
            BFrag A;
            A.u[0] = ((tg[0] == cls) ? 0x3F80u : 0u) | ((tg[2] == cls) ? 0x3F800000u : 0u);
            A.u[1] = ((tg[1] == cls) ? 0x3F80u : 0u) | ((tg[3] == cls) ? 0x3F800000u : 0u);
            A.u[2] = ((tg[4] == cls) ? 0x3F80u : 0u) | ((tg[6] == cls) ? 0x3F800000u : 0u);
            A.u[3] = ((tg[5] == cls) ? 0x3F80u : 0u) | ((tg[7] == cls) ? 0x3F800000u : 0u);
#pragma unroll
            for (int dt = 0; dt < 8; ++dt)
                acc[ct][dt] = __builtin_amdgcn_mfma_f32_16x16x32_bf16(A.v, B[dt].v,
                                                                      acc[ct][dt], 0, 0, 0);
        }
    }

    // wave-reduce sumsq
    float sq = sq0 + sq1;
    for (int o = 32; o > 0; o >>= 1) sq += __shfl_down(sq, o, 64);
    if (l == 0) lred[w] = sq;

    // ---- 8-wave pairwise tree in 2 regions (reuses staging LDS; fixed order) ----
    float* treeF = reinterpret_cast<float*>(sbuf);
#define TSTORE(region)                                                             \
    {                                                                              \
        float* dst = &treeF[(region) * (CLS * TPAD)];                              \
        _Pragma("unroll") for (int ct = 0; ct < 4; ++ct)                           \
            _Pragma("unroll") for (int dt = 0; dt < 8; ++dt)                       \
                _Pragma("unroll") for (int r = 0; r < 4; ++r)                      \
                    dst[(ct * 16 + lg * 4 + r) * TPAD + dt * 16 + li] =            \
                        acc[ct][dt][r];                                            \
    }
#define TADD(region)                                                               \
    {                                                                              \
        const float* src = &treeF[(region) * (CLS * TPAD)];                        \
        _Pragma("unroll") for (int ct = 0; ct < 4; ++ct)                           \
            _Pragma("unroll") for (int dt = 0; dt < 8; ++dt)                       \
                _Pragma("unroll") for (int r = 0; r < 4; ++r)                      \
                    acc[ct][dt][r] +=                                              \
                        src[(ct * 16 + lg * 4 + r) * TPAD + dt * 16 + li];         \
    }

    __syncthreads();
    if (w == 4) TSTORE(0);
    if (w == 5) TSTORE(1);
    __syncthreads();
    if (w == 0) TADD(0);
    if (w == 1) TADD(1);
    __syncthreads();
    if (w == 6) TSTORE(0);
    if (w == 7) TSTORE(1);
    __syncthreads();
    if (w == 2) TADD(0);
    if (w == 3) TADD(1);
    __syncthreads();
    if (w == 2) TSTORE(0);
    if (w == 3) TSTORE(1);
    __syncthreads();
    if (w == 0) TADD(0);
    if (w == 1) TADD(1);
    __syncthreads();
    if (w == 1) TSTORE(0);
    __syncthreads();

    if (w == 0) {
        TADD(0);
        float* __restrict__ ps = psum + (size_t)blockIdx.x * (CLS * DIM);
#pragma unroll
        for (int ct = 0; ct < 4; ++ct)
#pragma unroll
            for (int dt = 0; dt < 8; ++dt)
#pragma unroll
                for (int r = 0; r < 4; ++r)
                    ps[(ct * 16 + lg * 4 + r) * DIM + dt * 16 + li] = acc[ct][dt][r];
    }
    if (tid < CLS) pcnt[blockIdx.x * CLS + tid] = cnt[tid];
    if (tid == 0) {
        float tsum = 0.f;
        for (int k = 0; k < 8; ++k) tsum += lred[k];
        psq[blockIdx.x] = tsum;
    }
}

// ---------------- Phase B: deterministic partials reduction (256 partials) ----------------
__global__ __launch_bounds__(256) void phaseBR(const float* __restrict__ psum,
                                               const int* __restrict__ pcnt,
                                               const float* __restrict__ psq,
                                               float* __restrict__ fsum,
                                               int* __restrict__ fcnt,
                                               double* __restrict__ fsq) {
    const int tid = threadIdx.x;
    if (blockIdx.x < 128) {
        const int o = blockIdx.x * 64 + (tid & 63);
        const int q = tid >> 6;
        const float* __restrict__ p = psum + (size_t)q * 64 * (CLS * DIM) + o;
        float s0 = 0.f, s1 = 0.f, s2 = 0.f, s3 = 0.f;
        for (int j = 0; j < 64; j += 4) {
            s0 += p[(size_t)(j)     * (CLS * DIM)];
            s1 += p[(size_t)(j + 1) * (CLS * DIM)];
            s2 += p[(size_t)(j + 2) * (CLS * DIM)];
            s3 += p[(size_t)(j + 3) * (CLS * DIM)];
        }
        __shared__ float sh[4][64];
        sh[q][tid & 63] = (s0 + s1) + (s2 + s3);
        __syncthreads();
        if (tid < 64) fsum[o] = (sh[0][tid] + sh[1][tid]) + (sh[2][tid] + sh[3][tid]);
    } else {
        const int c = tid & 63;
        const int q = tid >> 6;
        int s = 0;
        for (int k = q * 64; k < q * 64 + 64; ++k) s += pcnt[k * CLS + c];
        __shared__ int shc[4][64];
        shc[q][c] = s;
        __syncthreads();
        if (tid < 64) fcnt[tid] = (shc[0][tid] + shc[1][tid]) + (shc[2][tid] + shc[3][tid]);
        if (tid < 64) {
            double d = 0.0;
            for (int k = tid; k < NBLK; k += 64) d += (double)psq[k];
            for (int o2 = 32; o2 > 0; o2 >>= 1) d += __shfl_down(d, o2, 64);
            if (tid == 0) fsq[0] = d;
        }
    }
}

// ---------------- Phase C: centers, l2 identity, pairwise margin via Gram ----------------
__device__ double blockReduceD(double v, double* scratch, int tid) {
    for (int o = 32; o > 0; o >>= 1) v += __shfl_down(v, o, 64);
    if ((tid & 63) == 0) scratch[tid >> 6] = v;
    __syncthreads();
    double t = 0.0;
    if (tid == 0) {
        for (int i = 0; i < 16; ++i) t += scratch[i];
    }
    __syncthreads();
    return t;
}

__global__ __launch_bounds__(1024) void phaseC(const float* __restrict__ fsum,
                                               const int* __restrict__ fcnt,
                                               const double* __restrict__ fsq,
                                               float* __restrict__ out) {
    __shared__ float cenT[DIM][CLS];
    __shared__ float nrm[CLS];
    __shared__ float cInv[CLS];
    __shared__ float cRaw[CLS];
    __shared__ double scratch[16];
    const int tid = threadIdx.x;

    if (tid < CLS) {
        float c = (float)fcnt[tid];
        cRaw[tid] = c;
        cInv[tid] = 1.f / (c + EPSF);
    }
    __syncthreads();

    double s1 = 0.0, s2 = 0.0;
    for (int i = tid; i < CLS * DIM; i += 1024) {
        const int c = i >> 7;
        const int d = i & 127;
        float v = fsum[i];
        float ctr = v * cInv[c];
        cenT[d][c] = ctr;
        s1 += (double)(v * ctr);
        s2 += (double)(cRaw[c] * ctr * ctr);
    }
    const double s1t = blockReduceD(s1, scratch, tid);
    const double s2t = blockReduceD(s2, scratch, tid);

    if (tid < CLS) {
        float n = 0.f;
        for (int d = 0; d < DIM; ++d) {
            float v = cenT[d][tid];
            n += v * v;
        }
        nrm[tid] = n;
    }
    __syncthreads();

    const int w = tid >> 6;
    const int b = tid & 63;
    float g0 = 0.f, g1 = 0.f, g2 = 0.f, g3 = 0.f;
    for (int d = 0; d < DIM; ++d) {
        float vb = cenT[d][b];
        g0 += cenT[d][w]      * vb;
        g1 += cenT[d][w + 16] * vb;
        g2 += cenT[d][w + 32] * vb;
        g3 += cenT[d][w + 48] * vb;
    }
    float ccp = 0.f;
    {
        float gs[4] = {g0, g1, g2, g3};
#pragma unroll
        for (int j = 0; j < 4; ++j) {
            const int a = w + 16 * j;
            if (a == b) continue;
            float d2 = nrm[a] + nrm[b] - 2.f * gs[j];
            float val = fmaxf(MARGIN - sqrtf(fmaxf(d2, 0.f) + EPSF), 0.f);
            ccp += val * val;
        }
    }
    const double ccOrd = blockReduceD((double)ccp, scratch, tid);

    if (tid == 0) {
        double triu = ccOrd * 0.5;
        double ccv = triu / 64.0 * 63.0 / 2.0;
        double l2 = (fsq[0] - 2.0 * s1t + s2t) / (double)NROWS;
        out[0] = (float)(l2 + ccv);
    }
}

extern "C" void kernel_launch(void* const* d_in, const int* in_sizes, int n_in,
                              void* d_out, int out_size, void* d_ws, size_t ws_size,
                              hipStream_t stream) {
    const float* emb = (const float*)d_in[0];
    const int* tgt = (const int*)d_in[1];
    float* out = (float*)d_out;

    char* ws = (char*)d_ws;
    float* fsum = (float*)ws;                              // 8192 floats @ 0
    int* fcnt = (int*)(ws + 32768);                        // 64 ints
    double* fsq = (double*)(ws + 33024);                   // 1 double (8-aligned)
    float* psum = (float*)(ws + 65536);                    // 256*8192 floats (8 MB)
    int* pcnt = (int*)(ws + 65536 + (size_t)NBLK * CLS * DIM * 4);      // 256*64 ints
    float* psq = (float*)(ws + 65536 + (size_t)NBLK * CLS * DIM * 4 + NBLK * CLS * 4);

    phaseA<<<NBLK, 512, 0, stream>>>(emb, tgt, psum, pcnt, psq);
    phaseBR<<<129, 256, 0, stream>>>(psum, pcnt, psq, fsum, fcnt, fsq);
    phaseC<<<1, 1024, 0, stream>>>(fsum, fcnt, fsq, out);
}

// Round 11
// 62.096 us; speedup vs baseline: 2.3253x; 2.3253x over previous
//
#include <hip/hip_runtime.h>

#define CLS 64
#define DIM 128
#define NROWS 262144
#define MARGIN 1.4f
#define EPSF 1e-6f
#define NBLK 256                   // 256 blocks x 512 thr (8 waves)
#define TPAD 132                   // padded tree row / staging slot pitch
#define SPITCH 132                 // staging: [16 slots][132] u32

typedef __attribute__((ext_vector_type(8))) short bf16x8;
typedef __attribute__((ext_vector_type(4))) float f32x4;
typedef __attribute__((ext_vector_type(4))) unsigned u32x4;

__device__ __forceinline__ bf16x8 as_bf16x8(u32x4 u) { return __builtin_bit_cast(bf16x8, u); }

// pack two fp32 into (bf16(hi)<<16)|bf16(lo) by truncation
__device__ __forceinline__ unsigned pack_bf16(float hi, float lo) {
    return (__float_as_uint(hi) & 0xFFFF0000u) | (__float_as_uint(lo) >> 16);
}

// ---------------- Phase A: one-hot MFMA class sums; coalesced loads + slot-major LDS staging ----------------
// Wave w owns rows [(b*8+w)*128, +128), 4 K-steps of 32 rows (REAL loop: unroll 1 to bound reg pressure).
// Staging per wave: [16 slots][SPITCH] u32. Slot s = 2m'+h holds rows (4m'+h, 4m'+h+2) packed (lo,hi).
//   write: lane (h,c) -> one ds_write_b128 at dword 132*s + 4c  (conflict-free)
//   read:  B[dt][j] = stage[(4lg+j)*132 + dt*16 + li]            (uniform 2-way = free)
__global__ __launch_bounds__(512, 2) void phaseA(const float* __restrict__ emb,
                                                 const int* __restrict__ tgt,
                                                 float* __restrict__ psum,
                                                 int* __restrict__ pcnt,
                                                 float* __restrict__ psq) {
    __shared__ __align__(16) unsigned sbuf[2 * CLS * TPAD];  // 16896 u32 = 8 waves x 16 x 132
    __shared__ int cnt[CLS];
    __shared__ float lred[8];

    const int tid = threadIdx.x;
    const int w = tid >> 6;          // wave 0..7
    const int l = tid & 63;
    const int h = l >> 5;            // row-parity half
    const int c = l & 31;            // dim-quad 0..31
    const int lg = (l >> 4) & 3;     // lane-group (k-block)
    const int li = l & 15;           // M/N lane index

    if (tid < CLS) cnt[tid] = 0;
    __syncthreads();

    unsigned* __restrict__ stage = &sbuf[w * (16 * SPITCH)];

    f32x4 acc[4][8];
#pragma unroll
    for (int ct = 0; ct < 4; ++ct)
#pragma unroll
        for (int dt = 0; dt < 8; ++dt) {
            f32x4 z = {0.f, 0.f, 0.f, 0.f};
            acc[ct][dt] = z;
        }

    float sq0 = 0.f, sq1 = 0.f;
    const float4* __restrict__ embv = reinterpret_cast<const float4*>(emb);
    const int wrow = blockIdx.x * 1024 + w * 128;

#pragma unroll 1
    for (int t = 0; t < 4; ++t) {
        const int rb = wrow + t * 32;

        // per-class counts (1 LDS-atomic instr per K-step)
        if (l < 32) atomicAdd(&cnt[tgt[rb + l]], 1);

        // tgt for this lane-group's 8 rows
        const int4* tp = reinterpret_cast<const int4*>(tgt + rb + lg * 8);
        const int4 ta = tp[0], tb = tp[1];

        // ---- stage 32 rows x 128 dims: coalesced float4 loads -> slot-major bf16 LDS ----
        const size_t fb = (size_t)rb * 32;    // float4 index of tile base
#pragma unroll
        for (int half = 0; half < 2; ++half) {
            float4 f[8];
#pragma unroll
            for (int i = 0; i < 8; ++i) f[i] = embv[fb + (size_t)(half * 8 + i) * 64 + l];
#pragma unroll
            for (int i = 0; i < 8; ++i) {
                sq0 += f[i].x * f[i].x + f[i].y * f[i].y;
                sq1 += f[i].z * f[i].z + f[i].w * f[i].w;
            }
            // pair (f[2m], f[2m+1]) = rows (4m'+h, 4m'+h+2), m' = half*4+m; slot s = 2m'+h
#pragma unroll
            for (int m = 0; m < 4; ++m) {
                const int s = (half * 4 + m) * 2 + h;
                const float4 lo = f[2 * m];
                const float4 hi = f[2 * m + 1];
                u32x4 pk;
                pk.x = pack_bf16(hi.x, lo.x);
                pk.y = pack_bf16(hi.y, lo.y);
                pk.z = pack_bf16(hi.z, lo.z);
                pk.w = pack_bf16(hi.w, lo.w);
                *reinterpret_cast<u32x4*>(&stage[s * SPITCH + 4 * c]) = pk;   // ds_write_b128
            }
        }

        // ---- B fragments: slots 4lg..4lg+3 at d = dt*16+li ----
        u32x4 B[8];
#pragma unroll
        for (int dt = 0; dt < 8; ++dt) {
            const int d = dt * 16 + li;
            u32x4 b;
            b.x = stage[(4 * lg + 0) * SPITCH + d];
            b.y = stage[(4 * lg + 1) * SPITCH + d];
            b.z = stage[(4 * lg + 2) * SPITCH + d];
            b.w = stage[(4 * lg + 3) * SPITCH + d];
            B[dt] = b;
        }

        // ---- A (one-hot, k-slot j -> rows {(0,2),(1,3),(4,6),(5,7)}+8lg) + MFMA ----
#pragma unroll
        for (int ct = 0; ct < 4; ++ct) {
            const int cls = ct * 16 + li;
            u32x4 A;
            A.x = ((ta.x == cls) ? 0x3F80u : 0u) | ((ta.z == cls) ? 0x3F800000u : 0u);
            A.y = ((ta.y == cls) ? 0x3F80u : 0u) | ((ta.w == cls) ? 0x3F800000u : 0u);
            A.z = ((tb.x == cls) ? 0x3F80u : 0u) | ((tb.z == cls) ? 0x3F800000u : 0u);
            A.w = ((tb.y == cls) ? 0x3F80u : 0u) | ((tb.w == cls) ? 0x3F800000u : 0u);
            const bf16x8 av = as_bf16x8(A);
#pragma unroll
            for (int dt = 0; dt < 8; ++dt)
                acc[ct][dt] = __builtin_amdgcn_mfma_f32_16x16x32_bf16(av, as_bf16x8(B[dt]),
                                                                      acc[ct][dt], 0, 0, 0);
        }
    }

    // wave-reduce sumsq
    float sq = sq0 + sq1;
    for (int o = 32; o > 0; o >>= 1) sq += __shfl_down(sq, o, 64);
    if (l == 0) lred[w] = sq;

    // ---- 8-wave pairwise tree in 2 regions (reuses staging LDS; fixed order) ----
    float* treeF = reinterpret_cast<float*>(sbuf);
#define TSTORE(region)                                                             \
    {                                                                              \
        float* dst = &treeF[(region) * (CLS * TPAD)];                              \
        _Pragma("unroll") for (int ct = 0; ct < 4; ++ct)                           \
            _Pragma("unroll") for (int dt = 0; dt < 8; ++dt)                       \
                _Pragma("unroll") for (int r = 0; r < 4; ++r)                      \
                    dst[(ct * 16 + lg * 4 + r) * TPAD + dt * 16 + li] =            \
                        acc[ct][dt][r];                                            \
    }
#define TADD(region)                                                               \
    {                                                                              \
        const float* src = &treeF[(region) * (CLS * TPAD)];                        \
        _Pragma("unroll") for (int ct = 0; ct < 4; ++ct)                           \
            _Pragma("unroll") for (int dt = 0; dt < 8; ++dt)                       \
                _Pragma("unroll") for (int r = 0; r < 4; ++r)                      \
                    acc[ct][dt][r] +=                                              \
                        src[(ct * 16 + lg * 4 + r) * TPAD + dt * 16 + li];         \
    }

    __syncthreads();
    if (w == 4) TSTORE(0);
    if (w == 5) TSTORE(1);
    __syncthreads();
    if (w == 0) TADD(0);
    if (w == 1) TADD(1);
    __syncthreads();
    if (w == 6) TSTORE(0);
    if (w == 7) TSTORE(1);
    __syncthreads();
    if (w == 2) TADD(0);
    if (w == 3) TADD(1);
    __syncthreads();
    if (w == 2) TSTORE(0);
    if (w == 3) TSTORE(1);
    __syncthreads();
    if (w == 0) TADD(0);
    if (w == 1) TADD(1);
    __syncthreads();
    if (w == 1) TSTORE(0);
    __syncthreads();

    if (w == 0) {
        TADD(0);
        float* __restrict__ ps = psum + (size_t)blockIdx.x * (CLS * DIM);
#pragma unroll
        for (int ct = 0; ct < 4; ++ct)
#pragma unroll
            for (int dt = 0; dt < 8; ++dt)
#pragma unroll
                for (int r = 0; r < 4; ++r)
                    ps[(ct * 16 + lg * 4 + r) * DIM + dt * 16 + li] = acc[ct][dt][r];
    }
    if (tid < CLS) pcnt[blockIdx.x * CLS + tid] = cnt[tid];
    if (tid == 0) {
        float tsum = 0.f;
        for (int k = 0; k < 8; ++k) tsum += lred[k];
        psq[blockIdx.x] = tsum;
    }
}

// ---------------- Phase B: deterministic partials reduction (256 partials) ----------------
__global__ __launch_bounds__(256) void phaseBR(const float* __restrict__ psum,
                                               const int* __restrict__ pcnt,
                                               const float* __restrict__ psq,
                                               float* __restrict__ fsum,
                                               int* __restrict__ fcnt,
                                               double* __restrict__ fsq) {
    const int tid = threadIdx.x;
    if (blockIdx.x < 128) {
        const int o = blockIdx.x * 64 + (tid & 63);
        const int q = tid >> 6;
        const float* __restrict__ p = psum + (size_t)q * 64 * (CLS * DIM) + o;
        float s0 = 0.f, s1 = 0.f, s2 = 0.f, s3 = 0.f;
        for (int j = 0; j < 64; j += 4) {
            s0 += p[(size_t)(j)     * (CLS * DIM)];
            s1 += p[(size_t)(j + 1) * (CLS * DIM)];
            s2 += p[(size_t)(j + 2) * (CLS * DIM)];
            s3 += p[(size_t)(j + 3) * (CLS * DIM)];
        }
        __shared__ float sh[4][64];
        sh[q][tid & 63] = (s0 + s1) + (s2 + s3);
        __syncthreads();
        if (tid < 64) fsum[o] = (sh[0][tid] + sh[1][tid]) + (sh[2][tid] + sh[3][tid]);
    } else {
        const int c = tid & 63;
        const int q = tid >> 6;
        int s = 0;
        for (int k = q * 64; k < q * 64 + 64; ++k) s += pcnt[k * CLS + c];
        __shared__ int shc[4][64];
        shc[q][c] = s;
        __syncthreads();
        if (tid < 64) fcnt[tid] = (shc[0][tid] + shc[1][tid]) + (shc[2][tid] + shc[3][tid]);
        if (tid < 64) {
            double d = 0.0;
            for (int k = tid; k < NBLK; k += 64) d += (double)psq[k];
            for (int o2 = 32; o2 > 0; o2 >>= 1) d += __shfl_down(d, o2, 64);
            if (tid == 0) fsq[0] = d;
        }
    }
}

// ---------------- Phase C: centers, l2 identity, pairwise margin via Gram ----------------
__device__ double blockReduceD(double v, double* scratch, int tid) {
    for (int o = 32; o > 0; o >>= 1) v += __shfl_down(v, o, 64);
    if ((tid & 63) == 0) scratch[tid >> 6] = v;
    __syncthreads();
    double t = 0.0;
    if (tid == 0) {
        for (int i = 0; i < 16; ++i) t += scratch[i];
    }
    __syncthreads();
    return t;
}

__global__ __launch_bounds__(1024) void phaseC(const float* __restrict__ fsum,
                                               const int* __restrict__ fcnt,
                                               const double* __restrict__ fsq,
                                               float* __restrict__ out) {
    __shared__ float cenT[DIM][CLS];
    __shared__ float nrm[CLS];
    __shared__ float cInv[CLS];
    __shared__ float cRaw[CLS];
    __shared__ double scratch[16];
    const int tid = threadIdx.x;

    if (tid < CLS) {
        float c = (float)fcnt[tid];
        cRaw[tid] = c;
        cInv[tid] = 1.f / (c + EPSF);
    }
    __syncthreads();

    double s1 = 0.0, s2 = 0.0;
    for (int i = tid; i < CLS * DIM; i += 1024) {
        const int c = i >> 7;
        const int d = i & 127;
        float v = fsum[i];
        float ctr = v * cInv[c];
        cenT[d][c] = ctr;
        s1 += (double)(v * ctr);
        s2 += (double)(cRaw[c] * ctr * ctr);
    }
    const double s1t = blockReduceD(s1, scratch, tid);
    const double s2t = blockReduceD(s2, scratch, tid);

    if (tid < CLS) {
        float n = 0.f;
        for (int d = 0; d < DIM; ++d) {
            float v = cenT[d][tid];
            n += v * v;
        }
        nrm[tid] = n;
    }
    __syncthreads();

    const int w = tid >> 6;
    const int b = tid & 63;
    float g0 = 0.f, g1 = 0.f, g2 = 0.f, g3 = 0.f;
    for (int d = 0; d < DIM; ++d) {
        float vb = cenT[d][b];
        g0 += cenT[d][w]      * vb;
        g1 += cenT[d][w + 16] * vb;
        g2 += cenT[d][w + 32] * vb;
        g3 += cenT[d][w + 48] * vb;
    }
    float ccp = 0.f;
    {
        float gs[4] = {g0, g1, g2, g3};
#pragma unroll
        for (int j = 0; j < 4; ++j) {
            const int a = w + 16 * j;
            if (a == b) continue;
            float d2 = nrm[a] + nrm[b] - 2.f * gs[j];
            float val = fmaxf(MARGIN - sqrtf(fmaxf(d2, 0.f) + EPSF), 0.f);
            ccp += val * val;
        }
    }
    const double ccOrd = blockReduceD((double)ccp, scratch, tid);

    if (tid == 0) {
        double triu = ccOrd * 0.5;
        double ccv = triu / 64.0 * 63.0 / 2.0;
        double l2 = (fsq[0] - 2.0 * s1t + s2t) / (double)NROWS;
        out[0] = (float)(l2 + ccv);
    }
}

extern "C" void kernel_launch(void* const* d_in, const int* in_sizes, int n_in,
                              void* d_out, int out_size, void* d_ws, size_t ws_size,
                              hipStream_t stream) {
    const float* emb = (const float*)d_in[0];
    const int* tgt = (const int*)d_in[1];
    float* out = (float*)d_out;

    char* ws = (char*)d_ws;
    float* fsum = (float*)ws;                              // 8192 floats @ 0
    int* fcnt = (int*)(ws + 32768);                        // 64 ints
    double* fsq = (double*)(ws + 33024);                   // 1 double (8-aligned)
    float* psum = (float*)(ws + 65536);                    // 256*8192 floats (8 MB)
    int* pcnt = (int*)(ws + 65536 + (size_t)NBLK * CLS * DIM * 4);      // 256*64 ints
    float* psq = (float*)(ws + 65536 + (size_t)NBLK * CLS * DIM * 4 + NBLK * CLS * 4);

    phaseA<<<NBLK, 512, 0, stream>>>(emb, tgt, psum, pcnt, psq);
    phaseBR<<<129, 256, 0, stream>>>(psum, pcnt, psq, fsum, fcnt, fsq);
    phaseC<<<1, 1024, 0, stream>>>(fsum, fcnt, fsq, out);
}